// Round 1
// baseline (887.573 us; speedup 1.0000x reference)
//
#include <hip/hip_runtime.h>
#include <cmath>

#define B_   4
#define N_   2466
#define R_   (B_*N_)     // 9864
#define ELLW 96
#define BM   64
#define BK   32

// ---------------- transpose [B,C,P] -> [B,P,C] ----------------
__global__ __launch_bounds__(256) void k_transpose(const float* __restrict__ in,
                                                   float* __restrict__ out,
                                                   int C, int P) {
  __shared__ float t[32][33];
  int b  = blockIdx.z;
  int p0 = blockIdx.x * 32, c0 = blockIdx.y * 32;
  int lp = threadIdx.x & 31, lc = threadIdx.x >> 5;
  for (int cc = lc; cc < 32; cc += 8) {
    int c = c0 + cc, p = p0 + lp;
    t[cc][lp] = (c < C && p < P) ? in[((size_t)b*C + c)*P + p] : 0.f;
  }
  __syncthreads();
  for (int pp = lc; pp < 32; pp += 8) {
    int p = p0 + pp, c = c0 + lp;
    if (p < P && c < C) out[((size_t)b*P + p)*C + c] = t[lp][pp];
  }
}

// ---------------- ELL build: one wave per adjacency row ----------------
__global__ __launch_bounds__(64) void k_ell(const float* __restrict__ A,
                                            int* __restrict__ cols,
                                            int* __restrict__ cnts) {
  int row  = blockIdx.x;
  int lane = threadIdx.x;
  const float* Ar = A + (size_t)row * N_;
  int* cp = cols + (size_t)row * ELLW;
  int base = 0;
  for (int j0 = 0; j0 < N_; j0 += 64) {
    int j = j0 + lane;
    bool nz = (j < N_) && (Ar[j] != 0.f);
    unsigned long long mk = __ballot(nz);
    int pos = __popcll(mk & ((1ull << lane) - 1ull));
    if (nz && base + pos < ELLW) cp[base + pos] = j;
    base += __popcll(mk);
  }
  if (lane == 0) cnts[row] = (base > ELLW) ? ELLW : base;
}

// ---------------- fused vertex-align gather + proj GEMM + concat ----------------
// Computes xcat[row][0:128]   = aligned@lin_w + lin_b
//          xcat[row][128:256] = vertex_features
//          xcat[row][256:259] = vertex_positions      (row stride 264)
__global__ __launch_bounds__(256) void k_align_gemm(
    const float* __restrict__ tr0, const float* __restrict__ tr1,
    const float* __restrict__ tr2, const float* __restrict__ tr3,
    const float* __restrict__ pos, const float* __restrict__ vf,
    const float* __restrict__ lin_w, const float* __restrict__ lin_b,
    float* __restrict__ xcat) {
  __shared__ float Xs[BK][BM + 1];
  __shared__ float Ws[BK][128];
  __shared__ int   sBase[BM][4];
  __shared__ float sWgt[BM][4];
  int tid = threadIdx.x;
  int m0  = blockIdx.x * BM;

  if (tid < BM) {
    int row = m0 + tid;
    const int Sarr[4] = {56, 28, 14, 7};
    const int Carr[4] = {256, 512, 1024, 2048};
    if (row < R_) {
      int b = row / N_;
      float px = pos[row*3+0], py = pos[row*3+1], pz = pos[row*3+2];
      float hh = fminf(fmaxf(248.f*(py/pz)    + 111.5f, 0.f), 223.f);
      float wc = fminf(fmaxf(248.f*(px/(-pz)) + 111.5f, 0.f), 223.f);
      #pragma unroll
      for (int s = 0; s < 4; s++) {
        int S = Sarr[s], C = Carr[s];
        float dv = 224.f / (float)S;
        float x = hh / dv, y = wc / dv;
        int x1 = (int)floorf(x), y1 = (int)floorf(y);
        int x2 = min((int)ceilf(x), S - 1), y2 = min((int)ceilf(y), S - 1);
        sWgt[tid][s]  = (float)((x2 - x1) * (y2 - y1));   // xi==x1, yi==y1 -> only tap (x1,y1) survives
        sBase[tid][s] = (b * S * S + x1 * S + y1) * C;    // NHWC base; add channel cc
      }
    } else {
      #pragma unroll
      for (int s = 0; s < 4; s++) { sWgt[tid][s] = 0.f; sBase[tid][s] = 0; }
    }
  }
  __syncthreads();

  float acc[8][4];
  #pragma unroll
  for (int r = 0; r < 8; r++)
    #pragma unroll
    for (int c = 0; c < 4; c++) acc[r][c] = 0.f;
  int cx = tid & 31, cy = tid >> 5;

  for (int k0 = 0; k0 < 3840; k0 += BK) {   // map boundaries (256,768,1792) are multiples of BK
    const float* tr; int off, sI;
    if (k0 < 256)       { tr = tr0; off = 0;    sI = 0; }
    else if (k0 < 768)  { tr = tr1; off = 256;  sI = 1; }
    else if (k0 < 1792) { tr = tr2; off = 768;  sI = 2; }
    else                { tr = tr3; off = 1792; sI = 3; }
    #pragma unroll
    for (int i = 0; i < 8; i++) {
      int e = tid + i * 256;
      int kk = e & 31, m = e >> 5;
      int cc = k0 - off + kk;
      Xs[kk][m] = sWgt[m][sI] * tr[sBase[m][sI] + cc];   // coalesced: lanes -> consecutive cc
    }
    #pragma unroll
    for (int i = 0; i < 4; i++) {
      int slot = tid + i * 256;
      int kk = slot >> 5, c4 = slot & 31;
      *(float4*)&Ws[kk][c4*4] = *(const float4*)&lin_w[(size_t)(k0 + kk)*128 + c4*4];
    }
    __syncthreads();
    #pragma unroll
    for (int kk = 0; kk < BK; kk++) {
      float a[8], bb[4];
      #pragma unroll
      for (int r = 0; r < 8; r++) a[r] = Xs[kk][cy*8 + r];
      #pragma unroll
      for (int c = 0; c < 4; c++) bb[c] = Ws[kk][cx*4 + c];
      #pragma unroll
      for (int r = 0; r < 8; r++)
        #pragma unroll
        for (int c = 0; c < 4; c++) acc[r][c] += a[r] * bb[c];
    }
    __syncthreads();
  }

  #pragma unroll
  for (int r = 0; r < 8; r++) {
    int row = m0 + cy*8 + r;
    if (row < R_) {
      int col = cx * 4;
      float4 v;
      v.x = acc[r][0] + lin_b[col+0];
      v.y = acc[r][1] + lin_b[col+1];
      v.z = acc[r][2] + lin_b[col+2];
      v.w = acc[r][3] + lin_b[col+3];
      *(float4*)&xcat[(size_t)row*264 + col] = v;
    }
  }
  for (int i = tid; i < BM*128; i += 256) {
    int m = i >> 7, c = i & 127;
    int row = m0 + m;
    if (row < R_) xcat[(size_t)row*264 + 128 + c] = vf[(size_t)row*128 + c];
  }
  for (int i = tid; i < BM*3; i += 256) {
    int m = i / 3, j = i - m*3;
    int row = m0 + m;
    if (row < R_) xcat[(size_t)row*264 + 256 + j] = pos[(size_t)row*3 + j];
  }
}

// ---------------- generic tiled GEMM: out[which] = X @ W[which] (+pb for which==2) ----------------
__global__ __launch_bounds__(256) void k_gemm(
    const float* __restrict__ X, int ldx, int K,
    const float* __restrict__ W0, const float* __restrict__ W1,
    const float* __restrict__ W2, const float* __restrict__ pb,
    float* __restrict__ o0, float* __restrict__ o1, float* __restrict__ o2) {
  __shared__ float Xs[BK][BM + 1];
  __shared__ float Ws[BK][128];
  int tid = threadIdx.x;
  int m0  = blockIdx.x * BM;
  int which = blockIdx.y;
  const float* W = (which == 0) ? W0 : (which == 1) ? W1 : W2;
  float* out     = (which == 0) ? o0 : (which == 1) ? o1 : o2;

  float acc[8][4];
  #pragma unroll
  for (int r = 0; r < 8; r++)
    #pragma unroll
    for (int c = 0; c < 4; c++) acc[r][c] = 0.f;
  int cx = tid & 31, cy = tid >> 5;

  for (int k0 = 0; k0 < K; k0 += BK) {
    #pragma unroll
    for (int i = 0; i < 8; i++) {
      int e = tid + i * 256;
      int kk = e & 31, m = e >> 5;
      int row = m0 + m, k = k0 + kk;
      Xs[kk][m] = (row < R_ && k < K) ? X[(size_t)row*ldx + k] : 0.f;
    }
    #pragma unroll
    for (int i = 0; i < 4; i++) {
      int slot = tid + i * 256;
      int kk = slot >> 5, c4 = slot & 31;
      int k = k0 + kk;
      float4 v = make_float4(0.f, 0.f, 0.f, 0.f);
      if (k < K) v = *(const float4*)&W[(size_t)k*128 + c4*4];
      *(float4*)&Ws[kk][c4*4] = v;
    }
    __syncthreads();
    #pragma unroll
    for (int kk = 0; kk < BK; kk++) {
      float a[8], bb[4];
      #pragma unroll
      for (int r = 0; r < 8; r++) a[r] = Xs[kk][cy*8 + r];
      #pragma unroll
      for (int c = 0; c < 4; c++) bb[c] = Ws[kk][cx*4 + c];
      #pragma unroll
      for (int r = 0; r < 8; r++)
        #pragma unroll
        for (int c = 0; c < 4; c++) acc[r][c] += a[r] * bb[c];
    }
    __syncthreads();
  }

  #pragma unroll
  for (int r = 0; r < 8; r++) {
    int row = m0 + cy*8 + r;
    if (row < R_) {
      int col = cx * 4;
      float4 v;
      v.x = acc[r][0]; v.y = acc[r][1]; v.z = acc[r][2]; v.w = acc[r][3];
      if (which == 2) { v.x += pb[col+0]; v.y += pb[col+1]; v.z += pb[col+2]; v.w += pb[col+3]; }
      *(float4*)&out[(size_t)row*128 + col] = v;
    }
  }
}

// ---------------- SpMM epilogue: out = [skip +] relu(s + A@t) ----------------
__global__ __launch_bounds__(128) void k_spmm(
    const float* __restrict__ sb, const float* __restrict__ tb,
    const int* __restrict__ cols, const int* __restrict__ cnts,
    const float* __restrict__ skip, float* __restrict__ out) {
  int row = blockIdx.x;
  int k   = threadIdx.x;
  int b   = row / N_;
  float acc = sb[(size_t)row*128 + k];
  int cnt = cnts[row];
  const int* cp = cols + (size_t)row * ELLW;
  size_t tbase = (size_t)b * N_;
  for (int i = 0; i < cnt; i++)
    acc += tb[(tbase + cp[i])*128 + k];
  acc = fmaxf(acc, 0.f);
  if (skip) acc += skip[(size_t)row*128 + k];
  out[(size_t)row*128 + k] = acc;
}

// ---------------- final 128->3 GEMV (both weights) ----------------
__global__ __launch_bounds__(64) void k_gf_gemv(
    const float* __restrict__ X, const float* __restrict__ w0,
    const float* __restrict__ w1, float* __restrict__ sb, float* __restrict__ tb) {
  int row = blockIdx.x, lane = threadIdx.x;
  float xa = X[(size_t)row*128 + lane];
  float xb = X[(size_t)row*128 + 64 + lane];
  #pragma unroll
  for (int c = 0; c < 3; c++) {
    float p = xa * w0[lane*3 + c] + xb * w0[(lane + 64)*3 + c];
    float q = xa * w1[lane*3 + c] + xb * w1[(lane + 64)*3 + c];
    #pragma unroll
    for (int off = 32; off > 0; off >>= 1) {
      p += __shfl_xor(p, off);
      q += __shfl_xor(q, off);
    }
    if (lane == 0) { sb[(size_t)row*128 + c] = p; tb[(size_t)row*128 + c] = q; }
  }
}

// ---------------- final: out = pos + tanh(relu(s + A@t)) ----------------
__global__ __launch_bounds__(64) void k_gf_final(
    const float* __restrict__ sb, const float* __restrict__ tb,
    const int* __restrict__ cols, const int* __restrict__ cnts,
    const float* __restrict__ pos, float* __restrict__ out) {
  int row = blockIdx.x, lane = threadIdx.x;
  if (lane >= 3) return;
  int b = row / N_;
  float acc = sb[(size_t)row*128 + lane];
  int cnt = cnts[row];
  const int* cp = cols + (size_t)row * ELLW;
  size_t tbase = (size_t)b * N_;
  for (int i = 0; i < cnt; i++)
    acc += tb[(tbase + cp[i])*128 + lane];
  float v = tanhf(fmaxf(acc, 0.f));
  out[(size_t)row*3 + lane] = pos[(size_t)row*3 + lane] + v;
}

extern "C" void kernel_launch(void* const* d_in, const int* in_sizes, int n_in,
                              void* d_out, int out_size, void* d_ws, size_t ws_size,
                              hipStream_t stream) {
  const float* conv2_3 = (const float*)d_in[0];
  const float* conv3_4 = (const float*)d_in[1];
  const float* conv4_6 = (const float*)d_in[2];
  const float* conv5_3 = (const float*)d_in[3];
  const float* pos     = (const float*)d_in[4];
  const float* vf      = (const float*)d_in[5];
  const float* adj     = (const float*)d_in[6];
  const float* lin_w   = (const float*)d_in[7];
  const float* lin_b   = (const float*)d_in[8];
  const float* r_pw[3]  = {(const float*)d_in[9],  (const float*)d_in[15], (const float*)d_in[21]};
  const float* r_pb[3]  = {(const float*)d_in[10], (const float*)d_in[16], (const float*)d_in[22]};
  const float* r_w00[3] = {(const float*)d_in[11], (const float*)d_in[17], (const float*)d_in[23]};
  const float* r_w01[3] = {(const float*)d_in[12], (const float*)d_in[18], (const float*)d_in[24]};
  const float* r_w10[3] = {(const float*)d_in[13], (const float*)d_in[19], (const float*)d_in[25]};
  const float* r_w11[3] = {(const float*)d_in[14], (const float*)d_in[20], (const float*)d_in[26]};
  const float* gf_w0 = (const float*)d_in[27];
  const float* gf_w1 = (const float*)d_in[28];
  float* out = (float*)d_out;

  // workspace layout (floats)
  float* ws  = (float*)d_ws;
  float* tr0 = ws;                                   // 4*256*3136  = 3,211,264
  float* tr1 = tr0 + (size_t)4*256*3136;             // 4*512*784   = 1,605,632
  float* tr2 = tr1 + (size_t)4*512*784;              // 4*1024*196  =   802,816
  float* tr3 = tr2 + (size_t)4*1024*196;             // 4*2048*49   =   401,408
  float* aft = tr3 + (size_t)4*2048*49;
  int*   ell_cnt  = (int*)aft;                       // R_
  int*   ell_cols = ell_cnt + R_;                    // R_*ELLW
  float* xcat = (float*)(ell_cols + (size_t)R_*ELLW);// R_*264
  float* sb   = xcat + (size_t)R_*264;               // R_*128
  float* tb   = sb   + (size_t)R_*128;
  float* skip = tb   + (size_t)R_*128;
  float* hb   = skip + (size_t)R_*128;
  float* xc   = hb   + (size_t)R_*128;

  // 1) NHWC transposes of the four feature maps (coalesced gather later)
  k_transpose<<<dim3(98, 8, 4),  256, 0, stream>>>(conv2_3, tr0, 256, 3136);
  k_transpose<<<dim3(25, 16, 4), 256, 0, stream>>>(conv3_4, tr1, 512, 784);
  k_transpose<<<dim3(7, 32, 4),  256, 0, stream>>>(conv4_6, tr2, 1024, 196);
  k_transpose<<<dim3(2, 64, 4),  256, 0, stream>>>(conv5_3, tr3, 2048, 49);

  // 2) sparse adjacency (0/1) -> ELL, built once, reused for all 7 graph convs
  k_ell<<<R_, 64, 0, stream>>>(adj, ell_cols, ell_cnt);

  // 3) fused align-gather + projection GEMM + concat
  k_align_gemm<<<155, 256, 0, stream>>>(tr0, tr1, tr2, tr3, pos, vf, lin_w, lin_b, xcat);

  // 4) three residual graph-conv blocks
  const float* xin = xcat; int ldx = 264, K = 259;
  for (int rb = 0; rb < 3; rb++) {
    k_gemm<<<dim3(155, 3), 256, 0, stream>>>(xin, ldx, K,
        r_w00[rb], r_w01[rb], r_pw[rb], r_pb[rb], sb, tb, skip);
    k_spmm<<<R_, 128, 0, stream>>>(sb, tb, ell_cols, ell_cnt, nullptr, hb);
    k_gemm<<<dim3(155, 2), 256, 0, stream>>>(hb, 128, 128,
        r_w10[rb], r_w11[rb], nullptr, nullptr, sb, tb, nullptr);
    k_spmm<<<R_, 128, 0, stream>>>(sb, tb, ell_cols, ell_cnt, skip, xc);
    xin = xc; ldx = 128; K = 128;
  }

  // 5) final graph conv (128->3) + tanh + residual add
  k_gf_gemv<<<R_, 64, 0, stream>>>(xc, gf_w0, gf_w1, sb, tb);
  k_gf_final<<<R_, 64, 0, stream>>>(sb, tb, ell_cols, ell_cnt, pos, out);
}

// Round 2
// 653.288 us; speedup vs baseline: 1.3586x; 1.3586x over previous
//
#include <hip/hip_runtime.h>
#include <cmath>

#define B_   4
#define N_   2466
#define R_   (B_*N_)     // 9864
#define ELLW 96
#define BK   32

// ---------------- transpose [B,C,P] -> [B,P,C] ----------------
__global__ __launch_bounds__(256) void k_transpose(const float* __restrict__ in,
                                                   float* __restrict__ out,
                                                   int C, int P) {
  __shared__ float t[32][33];
  int b  = blockIdx.z;
  int p0 = blockIdx.x * 32, c0 = blockIdx.y * 32;
  int lp = threadIdx.x & 31, lc = threadIdx.x >> 5;
  for (int cc = lc; cc < 32; cc += 8) {
    int c = c0 + cc, p = p0 + lp;
    t[cc][lp] = (c < C && p < P) ? in[((size_t)b*C + c)*P + p] : 0.f;
  }
  __syncthreads();
  for (int pp = lc; pp < 32; pp += 8) {
    int p = p0 + pp, c = c0 + lp;
    if (p < P && c < C) out[((size_t)b*P + p)*C + c] = t[lp][pp];
  }
}

// ---------------- ELL build: one wave per adjacency row ----------------
__global__ __launch_bounds__(64) void k_ell(const float* __restrict__ A,
                                            int* __restrict__ cols,
                                            int* __restrict__ cnts) {
  int row  = blockIdx.x;
  int lane = threadIdx.x;
  const float* Ar = A + (size_t)row * N_;
  int* cp = cols + (size_t)row * ELLW;
  int base = 0;
  for (int j0 = 0; j0 < N_; j0 += 64) {
    int j = j0 + lane;
    bool nz = (j < N_) && (Ar[j] != 0.f);
    unsigned long long mk = __ballot(nz);
    int pos = __popcll(mk & ((1ull << lane) - 1ull));
    if (nz && base + pos < ELLW) cp[base + pos] = j;
    base += __popcll(mk);
  }
  if (lane == 0) cnts[row] = (base > ELLW) ? ELLW : base;
}

// ---------------- split-K fused vertex-align gather + proj GEMM ----------------
// Each block computes a 64x128 partial over K-chunk [s*kchunk, (s+1)*kchunk),
// writing to part[(s*R_ + row)*128 + col].
__global__ __launch_bounds__(256) void k_align_gemm(
    const float* __restrict__ tr0, const float* __restrict__ tr1,
    const float* __restrict__ tr2, const float* __restrict__ tr3,
    const float* __restrict__ pos, const float* __restrict__ lin_w,
    float* __restrict__ part, int kchunk) {
  __shared__ float Xs[BK][65];
  __shared__ alignas(16) float Ws[BK][128];
  __shared__ int   sBase[64][4];
  __shared__ float sWgt[64][4];
  int tid = threadIdx.x;
  int m0  = blockIdx.x * 64;
  int s   = blockIdx.y;

  if (tid < 64) {
    int row = m0 + tid;
    const int Sarr[4] = {56, 28, 14, 7};
    const int Carr[4] = {256, 512, 1024, 2048};
    if (row < R_) {
      int b = row / N_;
      float px = pos[row*3+0], py = pos[row*3+1], pz = pos[row*3+2];
      float hh = fminf(fmaxf(248.f*(py/pz)    + 111.5f, 0.f), 223.f);
      float wc = fminf(fmaxf(248.f*(px/(-pz)) + 111.5f, 0.f), 223.f);
      #pragma unroll
      for (int q = 0; q < 4; q++) {
        int S = Sarr[q], C = Carr[q];
        float dv = 224.f / (float)S;
        float x = hh / dv, y = wc / dv;
        int x1 = (int)floorf(x), y1 = (int)floorf(y);
        int x2 = min((int)ceilf(x), S - 1), y2 = min((int)ceilf(y), S - 1);
        sWgt[tid][q]  = (float)((x2 - x1) * (y2 - y1));   // xi==x1,yi==y1 -> only (x1,y1) tap survives
        sBase[tid][q] = (b * S * S + x1 * S + y1) * C;    // NHWC base; add channel cc
      }
    } else {
      #pragma unroll
      for (int q = 0; q < 4; q++) { sWgt[tid][q] = 0.f; sBase[tid][q] = 0; }
    }
  }
  __syncthreads();

  float acc[8][4];
  #pragma unroll
  for (int r = 0; r < 8; r++)
    #pragma unroll
    for (int c = 0; c < 4; c++) acc[r][c] = 0.f;
  int cx = tid & 31, cy = tid >> 5;

  int kbeg = s * kchunk, kend = kbeg + kchunk;
  for (int k0 = kbeg; k0 < kend; k0 += BK) {   // section bounds (256,768,1792) are BK multiples
    const float* tr; int off, sI;
    if (k0 < 256)       { tr = tr0; off = 0;    sI = 0; }
    else if (k0 < 768)  { tr = tr1; off = 256;  sI = 1; }
    else if (k0 < 1792) { tr = tr2; off = 768;  sI = 2; }
    else                { tr = tr3; off = 1792; sI = 3; }
    #pragma unroll
    for (int i = 0; i < 8; i++) {
      int e = tid + i * 256;
      int kk = e & 31, m = e >> 5;
      int cc = k0 - off + kk;
      Xs[kk][m] = sWgt[m][sI] * tr[sBase[m][sI] + cc];   // lanes -> consecutive cc: coalesced
    }
    #pragma unroll
    for (int i = 0; i < 4; i++) {
      int slot = tid + i * 256;
      int kk = slot >> 5, c4 = slot & 31;
      *(float4*)&Ws[kk][c4*4] = *(const float4*)&lin_w[(size_t)(k0 + kk)*128 + c4*4];
    }
    __syncthreads();
    #pragma unroll
    for (int kk = 0; kk < BK; kk++) {
      float a[8], bb[4];
      #pragma unroll
      for (int r = 0; r < 8; r++) a[r] = Xs[kk][cy*8 + r];
      float4 bv = *(const float4*)&Ws[kk][cx*4];
      bb[0] = bv.x; bb[1] = bv.y; bb[2] = bv.z; bb[3] = bv.w;
      #pragma unroll
      for (int r = 0; r < 8; r++)
        #pragma unroll
        for (int c = 0; c < 4; c++) acc[r][c] += a[r] * bb[c];
    }
    __syncthreads();
  }

  #pragma unroll
  for (int r = 0; r < 8; r++) {
    int row = m0 + cy*8 + r;
    if (row < R_) {
      float4 v;
      v.x = acc[r][0]; v.y = acc[r][1]; v.z = acc[r][2]; v.w = acc[r][3];
      *(float4*)&part[((size_t)s*R_ + row)*128 + cx*4] = v;
    }
  }
}

// ---------------- reduce partials + bias, build xcat (proj|vf|pos) ----------------
__global__ __launch_bounds__(128) void k_reduce(
    const float* __restrict__ part, const float* __restrict__ lin_b,
    const float* __restrict__ vf, const float* __restrict__ pos,
    float* __restrict__ xcat, int nsplit) {
  int row = blockIdx.x, k = threadIdx.x;
  float acc = lin_b[k];
  for (int s = 0; s < nsplit; s++)
    acc += part[((size_t)s*R_ + row)*128 + k];
  xcat[(size_t)row*264 + k]       = acc;
  xcat[(size_t)row*264 + 128 + k] = vf[(size_t)row*128 + k];
  if (k < 3) xcat[(size_t)row*264 + 256 + k] = pos[(size_t)row*3 + k];
}

// ---------------- tiled GEMM (32x128 tile): out[which] = X @ W[which] (+pb for which==2) ----------------
__global__ __launch_bounds__(256) void k_gemm(
    const float* __restrict__ X, int ldx, int K,
    const float* __restrict__ W0, const float* __restrict__ W1,
    const float* __restrict__ W2, const float* __restrict__ pb,
    float* __restrict__ o0, float* __restrict__ o1, float* __restrict__ o2) {
  __shared__ float Xs[BK][33];
  __shared__ alignas(16) float Ws[BK][128];
  int tid = threadIdx.x;
  int m0  = blockIdx.x * 32;
  int which = blockIdx.y;
  const float* W = (which == 0) ? W0 : (which == 1) ? W1 : W2;
  float* out     = (which == 0) ? o0 : (which == 1) ? o1 : o2;

  float acc[4][4];
  #pragma unroll
  for (int r = 0; r < 4; r++)
    #pragma unroll
    for (int c = 0; c < 4; c++) acc[r][c] = 0.f;
  int cx = tid & 31, cy = tid >> 5;

  for (int k0 = 0; k0 < K; k0 += BK) {
    {
      int e = tid;                   // 1024 elems, 4 per thread
      #pragma unroll
      for (int i = 0; i < 4; i++) {
        int kk = e & 31, m = e >> 5;
        int row = m0 + m, k = k0 + kk;
        Xs[kk][m] = (row < R_ && k < K) ? X[(size_t)row*ldx + k] : 0.f;
        e += 256;
      }
    }
    #pragma unroll
    for (int i = 0; i < 4; i++) {
      int slot = tid + i * 256;
      int kk = slot >> 5, c4 = slot & 31;
      int k = k0 + kk;
      float4 v = make_float4(0.f, 0.f, 0.f, 0.f);
      if (k < K) v = *(const float4*)&W[(size_t)k*128 + c4*4];
      *(float4*)&Ws[kk][c4*4] = v;
    }
    __syncthreads();
    #pragma unroll
    for (int kk = 0; kk < BK; kk++) {
      float a[4];
      #pragma unroll
      for (int r = 0; r < 4; r++) a[r] = Xs[kk][cy*4 + r];
      float4 bv = *(const float4*)&Ws[kk][cx*4];
      float bb[4] = {bv.x, bv.y, bv.z, bv.w};
      #pragma unroll
      for (int r = 0; r < 4; r++)
        #pragma unroll
        for (int c = 0; c < 4; c++) acc[r][c] += a[r] * bb[c];
    }
    __syncthreads();
  }

  #pragma unroll
  for (int r = 0; r < 4; r++) {
    int row = m0 + cy*4 + r;
    if (row < R_) {
      int col = cx * 4;
      float4 v;
      v.x = acc[r][0]; v.y = acc[r][1]; v.z = acc[r][2]; v.w = acc[r][3];
      if (which == 2) { v.x += pb[col+0]; v.y += pb[col+1]; v.z += pb[col+2]; v.w += pb[col+3]; }
      *(float4*)&out[(size_t)row*128 + col] = v;
    }
  }
}

// ---------------- SpMM epilogue: out = [skip +] relu(s + A@t) ----------------
__global__ __launch_bounds__(128) void k_spmm(
    const float* __restrict__ sb, const float* __restrict__ tb,
    const int* __restrict__ cols, const int* __restrict__ cnts,
    const float* __restrict__ skip, float* __restrict__ out) {
  int row = blockIdx.x;
  int k   = threadIdx.x;
  int b   = row / N_;
  float acc = sb[(size_t)row*128 + k];
  int cnt = cnts[row];
  const int* cp = cols + (size_t)row * ELLW;
  size_t tbase = (size_t)b * N_;
  for (int i = 0; i < cnt; i++)
    acc += tb[(tbase + cp[i])*128 + k];
  acc = fmaxf(acc, 0.f);
  if (skip) acc += skip[(size_t)row*128 + k];
  out[(size_t)row*128 + k] = acc;
}

// ---------------- final 128->3 GEMV (both weights) ----------------
__global__ __launch_bounds__(64) void k_gf_gemv(
    const float* __restrict__ X, const float* __restrict__ w0,
    const float* __restrict__ w1, float* __restrict__ sb, float* __restrict__ tb) {
  int row = blockIdx.x, lane = threadIdx.x;
  float xa = X[(size_t)row*128 + lane];
  float xb = X[(size_t)row*128 + 64 + lane];
  #pragma unroll
  for (int c = 0; c < 3; c++) {
    float p = xa * w0[lane*3 + c] + xb * w0[(lane + 64)*3 + c];
    float q = xa * w1[lane*3 + c] + xb * w1[(lane + 64)*3 + c];
    #pragma unroll
    for (int off = 32; off > 0; off >>= 1) {
      p += __shfl_xor(p, off);
      q += __shfl_xor(q, off);
    }
    if (lane == 0) { sb[(size_t)row*128 + c] = p; tb[(size_t)row*128 + c] = q; }
  }
}

// ---------------- final: out = pos + tanh(relu(s + A@t)) ----------------
__global__ __launch_bounds__(64) void k_gf_final(
    const float* __restrict__ sb, const float* __restrict__ tb,
    const int* __restrict__ cols, const int* __restrict__ cnts,
    const float* __restrict__ pos, float* __restrict__ out) {
  int row = blockIdx.x, lane = threadIdx.x;
  if (lane >= 3) return;
  int b = row / N_;
  float acc = sb[(size_t)row*128 + lane];
  int cnt = cnts[row];
  const int* cp = cols + (size_t)row * ELLW;
  size_t tbase = (size_t)b * N_;
  for (int i = 0; i < cnt; i++)
    acc += tb[(tbase + cp[i])*128 + lane];
  float v = tanhf(fmaxf(acc, 0.f));
  out[(size_t)row*3 + lane] = pos[(size_t)row*3 + lane] + v;
}

extern "C" void kernel_launch(void* const* d_in, const int* in_sizes, int n_in,
                              void* d_out, int out_size, void* d_ws, size_t ws_size,
                              hipStream_t stream) {
  const float* conv2_3 = (const float*)d_in[0];
  const float* conv3_4 = (const float*)d_in[1];
  const float* conv4_6 = (const float*)d_in[2];
  const float* conv5_3 = (const float*)d_in[3];
  const float* pos     = (const float*)d_in[4];
  const float* vf      = (const float*)d_in[5];
  const float* adj     = (const float*)d_in[6];
  const float* lin_w   = (const float*)d_in[7];
  const float* lin_b   = (const float*)d_in[8];
  const float* r_pw[3]  = {(const float*)d_in[9],  (const float*)d_in[15], (const float*)d_in[21]};
  const float* r_pb[3]  = {(const float*)d_in[10], (const float*)d_in[16], (const float*)d_in[22]};
  const float* r_w00[3] = {(const float*)d_in[11], (const float*)d_in[17], (const float*)d_in[23]};
  const float* r_w01[3] = {(const float*)d_in[12], (const float*)d_in[18], (const float*)d_in[24]};
  const float* r_w10[3] = {(const float*)d_in[13], (const float*)d_in[19], (const float*)d_in[25]};
  const float* r_w11[3] = {(const float*)d_in[14], (const float*)d_in[20], (const float*)d_in[26]};
  const float* gf_w0 = (const float*)d_in[27];
  const float* gf_w1 = (const float*)d_in[28];
  float* out = (float*)d_out;

  // ---- workspace layout (floats) ----
  const size_t TR_TOT = (size_t)4*(256*3136 + 512*784 + 1024*196 + 2048*49); // 6,021,120
  const size_t ELL_I  = (size_t)R_ * (ELLW + 1);                             //   956,808 ints
  const size_t XCAT_F = (size_t)R_ * 264;                                    // 2,604,096

  float* ws  = (float*)d_ws;
  float* tr0 = ws;
  float* tr1 = tr0 + (size_t)4*256*3136;
  float* tr2 = tr1 + (size_t)4*512*784;
  float* tr3 = tr2 + (size_t)4*1024*196;
  int*   ell_cnt  = (int*)(tr3 + (size_t)4*2048*49);
  int*   ell_cols = ell_cnt + R_;
  float* xcat = (float*)(ell_cols + (size_t)R_*ELLW);
  float* buf  = xcat + XCAT_F;          // partials during align phase, then sb..xc
  float* sb   = buf;
  float* tb   = sb   + (size_t)R_*128;
  float* skip = tb   + (size_t)R_*128;
  float* hb   = skip + (size_t)R_*128;
  float* xc   = hb   + (size_t)R_*128;

  // adaptive split-K: 8 if workspace allows, else 4 (4 fits in the sb..xc region)
  size_t fixed_f = TR_TOT + ELL_I + XCAT_F;
  size_t need8   = (fixed_f + (size_t)8 * R_ * 128) * sizeof(float);
  int nsplit = (ws_size >= need8) ? 8 : 4;
  int kchunk = 3840 / nsplit;

  // 1) NHWC transposes of the four feature maps
  k_transpose<<<dim3(98, 8, 4),  256, 0, stream>>>(conv2_3, tr0, 256, 3136);
  k_transpose<<<dim3(25, 16, 4), 256, 0, stream>>>(conv3_4, tr1, 512, 784);
  k_transpose<<<dim3(7, 32, 4),  256, 0, stream>>>(conv4_6, tr2, 1024, 196);
  k_transpose<<<dim3(2, 64, 4),  256, 0, stream>>>(conv5_3, tr3, 2048, 49);

  // 2) adjacency (0/1) -> ELL, built once, reused for all 7 graph convs
  k_ell<<<R_, 64, 0, stream>>>(adj, ell_cols, ell_cnt);

  // 3) split-K fused align-gather + projection GEMM, then reduce+concat
  k_align_gemm<<<dim3(155, nsplit), 256, 0, stream>>>(tr0, tr1, tr2, tr3, pos, lin_w, buf, kchunk);
  k_reduce<<<R_, 128, 0, stream>>>(buf, lin_b, vf, pos, xcat, nsplit);

  // 4) three residual graph-conv blocks
  const float* xin = xcat; int ldx = 264, K = 259;
  for (int rb = 0; rb < 3; rb++) {
    k_gemm<<<dim3(309, 3), 256, 0, stream>>>(xin, ldx, K,
        r_w00[rb], r_w01[rb], r_pw[rb], r_pb[rb], sb, tb, skip);
    k_spmm<<<R_, 128, 0, stream>>>(sb, tb, ell_cols, ell_cnt, nullptr, hb);
    k_gemm<<<dim3(309, 2), 256, 0, stream>>>(hb, 128, 128,
        r_w10[rb], r_w11[rb], nullptr, nullptr, sb, tb, nullptr);
    k_spmm<<<R_, 128, 0, stream>>>(sb, tb, ell_cols, ell_cnt, skip, xc);
    xin = xc; ldx = 128; K = 128;
  }

  // 5) final graph conv (128->3) + tanh + residual add
  k_gf_gemv<<<R_, 64, 0, stream>>>(xc, gf_w0, gf_w1, sb, tb);
  k_gf_final<<<R_, 64, 0, stream>>>(sb, tb, ell_cols, ell_cnt, pos, out);
}